// Round 6
// baseline (2106.746 us; speedup 1.0000x reference)
//
#include <hip/hip_runtime.h>
#include <cstdint>

// FlowProjectionModule: forward-warp flow splatting + count-normalize + hole fill.
// B=16, C=2, H=720, W=1280, fp32 in/out.
//
// R3: harness poison-fills show ws_size ~450 MB -> single-chunk pipeline
// (16 images at once, runtime-guarded; exact old 2-chunk path as fallback).
// Hole compaction fused into accum_k epilogue (ballot already in regs).
// fillc_k: 4 lanes per hole (lane=direction, shfl_xor combine) -> kills
// per-thread serial 4-scan chain + 4x waves for latency hiding.

static constexpr int Bn = 16;
static constexpr int Hn = 720;
static constexpr int Wn = 1280;
static constexpr int HW = Hn * Wn;
static constexpr long long TOT = (long long)Bn * HW;    // 14,745,600
static constexpr int NBMAX = Bn * Hn;                   // 11520 max bins

static constexpr int RG   = 8;               // source rows per binning block
static constexpr int HALO = 64;              // |fy|<=64 via LDS hist; else global fallback
static constexpr int NH   = RG + 2 * HALO;   // 136 local bins
static constexpr int NW   = 16;              // waves per 1024-thread block

static constexpr int S  = 4;                 // target rows per accum strip
static constexpr int SW = S * Wn;            // 5120 cells

static constexpr int CW  = 12;               // u64 words per column mask (768 bits >= 720)
static constexpr int WPR = Wn / 64;          // 20 row-mask words per row
static constexpr int NWORDS = (int)(TOT / 64);           // 230,400 mask words

// ---------------- Pass A1: per-bin counts (per-wave sub-histograms) ----------------
__global__ __launch_bounds__(1024) void count_k(const float* __restrict__ flow,
                                                int* __restrict__ bin_count) {
    __shared__ int hist[NW][NH];             // 8704 B
    int bl = blockIdx.x / (Hn / RG);
    int g  = blockIdx.x % (Hn / RG);
    int y0 = g * RG;
    int wv = threadIdx.x >> 6;
    for (int i = threadIdx.x; i < NW * NH; i += 1024) ((int*)hist)[i] = 0;
    __syncthreads();

    const float* f = flow + (size_t)bl * 2 * HW;
    #pragma unroll
    for (int k = 0; k < 10; ++k) {
        int i  = threadIdx.x + k * 1024;     // RG*Wn = 10240 exactly
        int ry = i / Wn;
        int x  = i - ry * Wn;
        int y  = y0 + ry;
        int p  = y * Wn + x;
        float fx = f[p];
        float fy = f[p + HW];
        float x2 = (float)x + fx;
        float y2 = (float)y + fy;
        if (!(x2 >= 0.f && y2 >= 0.f && x2 <= (float)(Wn - 1) && y2 <= (float)(Hn - 1)))
            continue;
        int yT  = (int)floorf(y2);
        int rel = yT - y0 + HALO;
        if (rel >= 0 && rel < NH) atomicAdd(&hist[wv][rel], 1);
        else                      atomicAdd(&bin_count[bl * Hn + yT], 1);   // outlier
    }
    __syncthreads();
    for (int i = threadIdx.x; i < NH; i += 1024) {
        int tot = 0;
        for (int w = 0; w < NW; ++w) tot += hist[w][i];
        int row = y0 - HALO + i;
        if (tot > 0 && row >= 0 && row < Hn)
            atomicAdd(&bin_count[bl * Hn + row], tot);
    }
}

// ---------------- Pass A2: exclusive scan of nb bins (single block) ----------------
__global__ __launch_bounds__(1024) void scan_k(const int* __restrict__ bin_count,
                                               int* __restrict__ off,
                                               int* __restrict__ cur,
                                               int nb) {
    __shared__ int s[1024];
    const int PER = 12;                      // covers up to 12288 bins
    int t  = threadIdx.x;
    int lo = t * PER;
    int local[PER];
    int sum = 0;
    for (int k = 0; k < PER; ++k) {
        int i = lo + k;
        int v = (i < nb) ? bin_count[i] : 0;
        local[k] = v;
        sum += v;
    }
    s[t] = sum;
    __syncthreads();
    for (int d = 1; d < 1024; d <<= 1) {
        int v = (t >= d) ? s[t - d] : 0;
        __syncthreads();
        s[t] += v;
        __syncthreads();
    }
    int base = s[t] - sum;
    for (int k = 0; k < PER; ++k) {
        int i = lo + k;
        if (i < nb) {
            off[i] = base;
            cur[i] = base;
            base += local[k];
        }
    }
    if (t == 1023) off[nb] = s[1023];
}

// ---------------- Pass A3: emit packed u64 records into bin segments ----------------
// record: [fyq_b:19 @41][fxq_b:19 @22][yT:11 @11][xL:11 @0], q = round(-f*128)+2^18
__global__ __launch_bounds__(1024) void emit_k(const float* __restrict__ flow,
                                               int* __restrict__ cur,
                                               unsigned long long* __restrict__ recs) {
    __shared__ int hist[NW][NH];             // counts, then absolute per-wave cursors
    int bl = blockIdx.x / (Hn / RG);
    int g  = blockIdx.x % (Hn / RG);
    int y0 = g * RG;
    int wv = threadIdx.x >> 6;
    for (int i = threadIdx.x; i < NW * NH; i += 1024) ((int*)hist)[i] = 0;
    __syncthreads();

    const float* f = flow + (size_t)bl * 2 * HW;
    float cfx[10], cfy[10];
    #pragma unroll
    for (int k = 0; k < 10; ++k) {
        int i  = threadIdx.x + k * 1024;
        int ry = i / Wn;
        int x  = i - ry * Wn;
        int y  = y0 + ry;
        int p  = y * Wn + x;
        float fx = f[p];
        float fy = f[p + HW];
        cfx[k] = fx;
        cfy[k] = fy;
        float x2 = (float)x + fx;
        float y2 = (float)y + fy;
        if (!(x2 >= 0.f && y2 >= 0.f && x2 <= (float)(Wn - 1) && y2 <= (float)(Hn - 1)))
            continue;
        int yT  = (int)floorf(y2);
        int rel = yT - y0 + HALO;
        if (rel >= 0 && rel < NH) atomicAdd(&hist[wv][rel], 1);
    }
    __syncthreads();
    for (int i = threadIdx.x; i < NH; i += 1024) {
        int tot = 0;
        for (int w = 0; w < NW; ++w) tot += hist[w][i];
        int row = y0 - HALO + i;
        int run = 0;
        if (tot > 0 && row >= 0 && row < Hn)
            run = atomicAdd(&cur[bl * Hn + row], tot);
        for (int w = 0; w < NW; ++w) {
            int c = hist[w][i];
            hist[w][i] = run;
            run += c;
        }
    }
    __syncthreads();
    #pragma unroll
    for (int k = 0; k < 10; ++k) {
        int i  = threadIdx.x + k * 1024;
        int ry = i / Wn;
        int x  = i - ry * Wn;
        int y  = y0 + ry;
        float fx = cfx[k];
        float fy = cfy[k];
        float x2 = (float)x + fx;
        float y2 = (float)y + fy;
        if (!(x2 >= 0.f && y2 >= 0.f && x2 <= (float)(Wn - 1) && y2 <= (float)(Hn - 1)))
            continue;
        int xL = (int)floorf(x2); xL = max(0, min(xL, Wn - 1));
        int yT = (int)floorf(y2);
        int fxq = __float2int_rn(-fx * 128.f) + (1 << 18);   // in (0, 2^19)
        int fyq = __float2int_rn(-fy * 128.f) + (1 << 18);
        unsigned long long rec = (unsigned long long)(unsigned)xL
                               | ((unsigned long long)(unsigned)yT  << 11)
                               | ((unsigned long long)(unsigned)fxq << 22)
                               | ((unsigned long long)(unsigned)fyq << 41);
        int rel = yT - y0 + HALO;
        int slot;
        if (rel >= 0 && rel < NH) slot = atomicAdd(&hist[wv][rel], 1);
        else                      slot = atomicAdd(&cur[bl * Hn + yT], 1);   // outlier
        recs[slot] = rec;
    }
}

// ---------------- Pass B: strip u64-packed LDS accumulation + fused normalize ----------------
// If holes != nullptr, also emits compacted hole indices (fused compact_k).
__global__ __launch_bounds__(512, 8) void accum_k(const int* __restrict__ off,
                                                  const unsigned long long* __restrict__ recs,
                                                  float* __restrict__ out,
                                                  unsigned long long* __restrict__ mask,
                                                  unsigned* __restrict__ holes,
                                                  unsigned* __restrict__ hole_cnt) {
    __shared__ unsigned long long accQ[SW];  // 40 KB: [fy:27][fx:27][cnt:10] per cell
    int bl = blockIdx.x / (Hn / S);
    int st = blockIdx.x % (Hn / S);
    int r0 = st * S;

    for (int i = threadIdx.x; i < SW; i += 512) accQ[i] = 0ull;
    __syncthreads();

    int rlo = max(r0 - 1, 0);
    int rhi = r0 + S - 1;
    int lo  = off[bl * Hn + rlo];
    int hi  = off[bl * Hn + rhi + 1];

    for (int j = lo + threadIdx.x; j < hi; j += 512) {
        unsigned long long rec = recs[j];
        int xL = (int)(rec & 0x7FFu);
        int yT = (int)((rec >> 11) & 0x7FFu);
        unsigned long long t = (((rec >> 41) & 0x7FFFFull) << 37)
                             | (((rec >> 22) & 0x7FFFFull) << 10) | 1ull;
        int xR = min(xL + 1, Wn - 1);
        int yB = min(yT + 1, Hn - 1);
        #pragma unroll
        for (int rr = 0; rr < 2; ++rr) {
            int row = rr ? yB : yT;          // yT==yB at bottom edge -> double add (matches ref)
            if (row >= r0 && row < r0 + S) {
                int rb = (row - r0) * Wn;
                atomicAdd(&accQ[rb + xL], t);
                atomicAdd(&accQ[rb + xR], t);   // xL==xR at right edge -> double add
            }
        }
    }
    __syncthreads();

    float* ox = out + (size_t)bl * 2 * HW;
    size_t pixbase = (size_t)bl * HW + (size_t)r0 * Wn;  // multiple of 64
    int lane = threadIdx.x & 63;
    for (int i = threadIdx.x; i < SW; i += 512) {        // 10 iters, all lanes active
        int rw  = i / Wn;
        int col = i - rw * Wn;
        int p   = (r0 + rw) * Wn + col;
        unsigned long long v = accQ[i];
        unsigned c = (unsigned)(v & 1023ull);
        float vx = 0.f, vy = 0.f;
        if (c) {
            int sfx = (int)((v >> 10) & 0x7FFFFFFull) - (int)(c << 18);
            int sfy = (int)((v >> 37) & 0x7FFFFFFull) - (int)(c << 18);
            float inv = 1.f / (128.f * (float)c);
            vx = (float)sfx * inv;
            vy = (float)sfy * inv;
        }
        ox[p]      = vx;
        ox[p + HW] = vy;
        unsigned long long m = __ballot(c != 0);
        if (lane == 0) mask[(pixbase + (size_t)i) >> 6] = m;
        if (holes) {                                   // fused hole compaction
            unsigned long long hb = ~m;
            if (hb) {
                unsigned base = 0;
                if (lane == 0) base = atomicAdd(hole_cnt, (unsigned)__popcll(hb));
                base = (unsigned)__shfl((int)base, 0);
                unsigned long long lt = (1ull << lane) - 1ull;
                if (!c) holes[base + (unsigned)__popcll(hb & lt)] = (unsigned)(pixbase + (size_t)i);
            }
        }
    }
}

// ---------------- bit-transpose row mask -> column mask ----------------
// colmask[(b*Wn + x)*CW + w] bit j = mask bit for (b, row w*64+j, col x).
// In-register 64x64 bit transpose per wave (Hacker's Delight butterfly).
__global__ __launch_bounds__(256) void transpose_k(const unsigned long long* __restrict__ mask,
                                                   unsigned long long* __restrict__ colmask) {
    int tile = blockIdx.x * 4 + (threadIdx.x >> 6);   // (b, tY, xw)
    int lane = threadIdx.x & 63;
    int xw = tile % WPR;
    int tY = (tile / WPR) % CW;
    int b  = tile / (WPR * CW);
    int y  = tY * 64 + lane;

    unsigned long long x = 0ull;
    if (y < Hn) x = mask[(size_t)b * (HW / 64) + (size_t)y * WPR + xw];
    x = __builtin_bitreverse64(x);           // MSB-first convention for HD transpose

    unsigned long long m = 0x00000000FFFFFFFFull;
    #pragma unroll
    for (int j = 32; j != 0; j >>= 1, m ^= (m << j)) {
        unsigned long long p = __shfl_xor(x, j);
        bool hi = (lane & j) != 0;
        unsigned long long lo_w = hi ? p : x;
        unsigned long long hi_w = hi ? x : p;
        unsigned long long t = (lo_w ^ (hi_w >> j)) & m;
        x ^= hi ? (t << j) : t;
    }
    x = __builtin_bitreverse64(x);           // back to LSB = smallest row

    int col = xw * 64 + lane;
    colmask[((size_t)b * Wn + col) * CW + tY] = x;
}

// ---------------- compact holes into a dense list (fallback path only) ----------------
__global__ __launch_bounds__(256) void compact_k(const unsigned long long* __restrict__ mask,
                                                 unsigned* __restrict__ holes,
                                                 unsigned* __restrict__ hole_cnt) {
    int w = blockIdx.x * 256 + threadIdx.x;          // grid sized exactly NWORDS
    int lane = threadIdx.x & 63;
    unsigned long long hb = ~mask[w];
    int cnt = __popcll(hb);
    int incl = cnt;
    #pragma unroll
    for (int d = 1; d < 64; d <<= 1) {
        int v = __shfl_up(incl, d);
        if (lane >= d) incl += v;
    }
    int total = __shfl(incl, 63);
    unsigned base = 0;
    if (total > 0) {
        if (lane == 63) base = atomicAdd(hole_cnt, (unsigned)total);
        base = (unsigned)__shfl((int)base, 63);
    }
    unsigned slot = base + (unsigned)(incl - cnt);
    unsigned gpb = (unsigned)w << 6;
    while (hb) {
        int b = __ffsll((long long)hb) - 1;
        holes[slot++] = gpb + (unsigned)b;
        hb &= hb - 1;
    }
}

// ---------------- hole fill: 4 lanes per hole (lane = direction) ----------------
__global__ __launch_bounds__(256) void fillc_k(float* __restrict__ out,
                                               const unsigned long long* __restrict__ mask,
                                               const unsigned long long* __restrict__ colmask,
                                               const unsigned* __restrict__ holes,
                                               const unsigned* __restrict__ hole_cnt) {
    int n = (int)*hole_cnt;
    long long tot = (long long)n << 2;
    for (long long i = (long long)blockIdx.x * 256 + threadIdx.x; i < tot;
         i += (long long)gridDim.x * 256) {
        int idx = (int)(i >> 2);
        int dir = (int)(i & 3);
        unsigned gp = holes[idx];
        int b = (int)(gp / (unsigned)HW);
        int p = (int)(gp - (unsigned)b * (unsigned)HW);
        int y = p / Wn;
        int x = p - y * Wn;
        float* ox = out + (size_t)b * 2 * HW;

        int q = -1;
        if (dir < 2) {
            const unsigned long long* rowmask = mask + (((size_t)b * HW + (size_t)y * Wn) >> 6);
            int bit = x & 63;
            if (dir == 0) {                  // nearest valid LEFT
                int w = x >> 6;
                unsigned long long m = bit ? (rowmask[w] & ((1ull << bit) - 1)) : 0ull;
                while (true) {
                    if (m) { q = y * Wn + ((w << 6) + 63 - __clzll(m)); break; }
                    if (--w < 0) break;
                    m = rowmask[w];
                }
            } else {                         // nearest valid RIGHT
                int w = x >> 6;
                unsigned long long m = rowmask[w] & ~((2ull << bit) - 1);   // bits > bit
                while (true) {
                    if (m) { q = y * Wn + ((w << 6) + __ffsll((long long)m) - 1); break; }
                    if (++w >= WPR) break;
                    m = rowmask[w];
                }
            }
        } else {
            const unsigned long long* cm = colmask + ((size_t)b * Wn + x) * CW;
            int rb = y & 63;
            if (dir == 2) {                  // nearest valid UP
                int w = y >> 6;
                unsigned long long m = rb ? (cm[w] & ((1ull << rb) - 1)) : 0ull;
                while (true) {
                    if (m) { q = ((w << 6) + 63 - __clzll(m)) * Wn + x; break; }
                    if (--w < 0) break;
                    m = cm[w];
                }
            } else {                         // nearest valid DOWN (bits >= Hn are 0)
                int w = y >> 6;
                unsigned long long m = cm[w] & ~((2ull << rb) - 1);
                while (true) {
                    if (m) { q = ((w << 6) + __ffsll((long long)m) - 1) * Wn + x; break; }
                    if (++w >= CW) break;
                    m = cm[w];
                }
            }
        }

        float vx = 0.f, vy = 0.f, fnd = 0.f;
        if (q >= 0) { vx = ox[q]; vy = ox[q + HW]; fnd = 1.f; }
        vx += __shfl_xor(vx, 1); vy += __shfl_xor(vy, 1); fnd += __shfl_xor(fnd, 1);
        vx += __shfl_xor(vx, 2); vy += __shfl_xor(vy, 2); fnd += __shfl_xor(fnd, 2);
        if (dir == 0 && fnd > 0.f) {
            ox[p]      = vx / fnd;
            ox[p + HW] = vy / fnd;
        }
    }
}

extern "C" void kernel_launch(void* const* d_in, const int* in_sizes, int n_in,
                              void* d_out, int out_size, void* d_ws, size_t ws_size,
                              hipStream_t stream) {
    const float* flow = (const float*)d_in[0];
    float* out = (float*)d_out;
    char* ws = (char*)d_ws;

    // ---- big layout (single chunk, 16 images): ~181 MB ----
    size_t recs16_b = (size_t)Bn * HW * 8;                 // 118.0 MB
    size_t mask_b   = (size_t)(TOT / 64) * 8;              // 1.84 MB
    size_t col_b    = (size_t)Bn * Wn * CW * 8;            // 1.97 MB
    size_t holes_b  = (size_t)TOT * 4;                     // 59.0 MB
    size_t bins_b   = 4 * ((size_t)NBMAX * 4 + 256) + ((size_t)(NBMAX + 1) * 4) + 512;
    size_t need_big = recs16_b + mask_b + col_b + holes_b + bins_b + 4096;
    bool big = ws_size >= need_big;

    int hbImgs = big ? 16 : 8;               // images per chunk
    int chunks = big ? 1 : 2;
    int nb = hbImgs * Hn;                    // bins per chunk
    size_t recs_b = (size_t)hbImgs * HW * 8;

    size_t o = 0;
    unsigned long long* recs = (unsigned long long*)(ws + o); o += recs_b;
    unsigned long long* mask = (unsigned long long*)(ws + o); o += mask_b;
    unsigned long long* colmask = (unsigned long long*)(ws + o); o += col_b;
    unsigned* holes;
    if (big) { holes = (unsigned*)(ws + o); o += holes_b; }
    else     { holes = (unsigned*)recs; }    // recs dead before compact_k in fallback
    o = (o + 255) & ~(size_t)255;
    int* bin_count = (int*)(ws + o); o += (size_t)NBMAX * 4;
    o = (o + 255) & ~(size_t)255;
    int* off = (int*)(ws + o);       o += (size_t)(NBMAX + 1) * 4;
    o = (o + 255) & ~(size_t)255;
    int* cur = (int*)(ws + o);       o += (size_t)NBMAX * 4;
    o = (o + 255) & ~(size_t)255;
    unsigned* hole_cnt = (unsigned*)(ws + o); o += 4;

    const int bin_blocks   = hbImgs * (Hn / RG);   // 1440 (big) / 720
    const int strip_blocks = hbImgs * (Hn / S);    // 2880 (big) / 1440

    hipMemsetAsync(hole_cnt, 0, 4, stream);

    for (int chunk = 0; chunk < chunks; ++chunk) {
        const float* fchunk = flow + (size_t)chunk * hbImgs * 2 * HW;
        float* ochunk = out + (size_t)chunk * hbImgs * 2 * HW;
        unsigned long long* mchunk = mask + (size_t)chunk * ((size_t)hbImgs * HW / 64);

        hipMemsetAsync(bin_count, 0, (size_t)nb * 4, stream);
        count_k<<<bin_blocks, 1024, 0, stream>>>(fchunk, bin_count);
        scan_k<<<1, 1024, 0, stream>>>(bin_count, off, cur, nb);
        emit_k<<<bin_blocks, 1024, 0, stream>>>(fchunk, cur, recs);
        accum_k<<<strip_blocks, 512, 0, stream>>>(off, recs, ochunk, mchunk,
                                                  big ? holes : nullptr, hole_cnt);
    }

    const int tr_tiles = Bn * CW * WPR;                 // 3840 tiles
    transpose_k<<<tr_tiles / 4, 256, 0, stream>>>(mask, colmask);
    if (!big)
        compact_k<<<NWORDS / 256, 256, 0, stream>>>(mask, holes, hole_cnt);
    fillc_k<<<2048, 256, 0, stream>>>(out, mask, colmask, holes, hole_cnt);
}

// Round 10
// 432.657 us; speedup vs baseline: 4.8693x; 4.8693x over previous
//
#include <hip/hip_runtime.h>
#include <cstdint>

// FlowProjectionModule: forward-warp flow splatting + count-normalize + hole fill.
// B=16, C=2, H=720, W=1280, fp32 in/out.
//
// R6 post-mortem: fused hole compaction in accum_k = ~160K device-scope
// atomics on ONE address (hole_cnt) -> 1783us, VALUBusy 1.9%. REVERTED to
// separate compact_k (3600 wave-atomics, proven fast in R2).
// Kept from R3: single-chunk pipeline (ws allows 122MB), 4-lane-per-hole
// fillc_k (lane=direction), fused mask from accum, bit-transposed colmask.

static constexpr int Bn = 16;
static constexpr int Hn = 720;
static constexpr int Wn = 1280;
static constexpr int HW = Hn * Wn;
static constexpr long long TOT = (long long)Bn * HW;    // 14,745,600
static constexpr int NBMAX = Bn * Hn;                   // 11520 max bins

static constexpr int RG   = 8;               // source rows per binning block
static constexpr int HALO = 64;              // |fy|<=64 via LDS hist; else global fallback
static constexpr int NH   = RG + 2 * HALO;   // 136 local bins
static constexpr int NW   = 16;              // waves per 1024-thread block

static constexpr int S  = 4;                 // target rows per accum strip
static constexpr int SW = S * Wn;            // 5120 cells

static constexpr int CW  = 12;               // u64 words per column mask (768 bits >= 720)
static constexpr int WPR = Wn / 64;          // 20 row-mask words per row
static constexpr int NWORDS = (int)(TOT / 64);           // 230,400 mask words

// ---------------- Pass A1: per-bin counts (per-wave sub-histograms) ----------------
__global__ __launch_bounds__(1024) void count_k(const float* __restrict__ flow,
                                                int* __restrict__ bin_count) {
    __shared__ int hist[NW][NH];             // 8704 B
    int bl = blockIdx.x / (Hn / RG);
    int g  = blockIdx.x % (Hn / RG);
    int y0 = g * RG;
    int wv = threadIdx.x >> 6;
    for (int i = threadIdx.x; i < NW * NH; i += 1024) ((int*)hist)[i] = 0;
    __syncthreads();

    const float* f = flow + (size_t)bl * 2 * HW;
    #pragma unroll
    for (int k = 0; k < 10; ++k) {
        int i  = threadIdx.x + k * 1024;     // RG*Wn = 10240 exactly
        int ry = i / Wn;
        int x  = i - ry * Wn;
        int y  = y0 + ry;
        int p  = y * Wn + x;
        float fx = f[p];
        float fy = f[p + HW];
        float x2 = (float)x + fx;
        float y2 = (float)y + fy;
        if (!(x2 >= 0.f && y2 >= 0.f && x2 <= (float)(Wn - 1) && y2 <= (float)(Hn - 1)))
            continue;
        int yT  = (int)floorf(y2);
        int rel = yT - y0 + HALO;
        if (rel >= 0 && rel < NH) atomicAdd(&hist[wv][rel], 1);
        else                      atomicAdd(&bin_count[bl * Hn + yT], 1);   // outlier
    }
    __syncthreads();
    for (int i = threadIdx.x; i < NH; i += 1024) {
        int tot = 0;
        for (int w = 0; w < NW; ++w) tot += hist[w][i];
        int row = y0 - HALO + i;
        if (tot > 0 && row >= 0 && row < Hn)
            atomicAdd(&bin_count[bl * Hn + row], tot);
    }
}

// ---------------- Pass A2: exclusive scan of nb bins (single block) ----------------
__global__ __launch_bounds__(1024) void scan_k(const int* __restrict__ bin_count,
                                               int* __restrict__ off,
                                               int* __restrict__ cur,
                                               int nb) {
    __shared__ int s[1024];
    const int PER = 12;                      // covers up to 12288 bins
    int t  = threadIdx.x;
    int lo = t * PER;
    int local[PER];
    int sum = 0;
    for (int k = 0; k < PER; ++k) {
        int i = lo + k;
        int v = (i < nb) ? bin_count[i] : 0;
        local[k] = v;
        sum += v;
    }
    s[t] = sum;
    __syncthreads();
    for (int d = 1; d < 1024; d <<= 1) {
        int v = (t >= d) ? s[t - d] : 0;
        __syncthreads();
        s[t] += v;
        __syncthreads();
    }
    int base = s[t] - sum;
    for (int k = 0; k < PER; ++k) {
        int i = lo + k;
        if (i < nb) {
            off[i] = base;
            cur[i] = base;
            base += local[k];
        }
    }
    if (t == 1023) off[nb] = s[1023];
}

// ---------------- Pass A3: emit packed u64 records into bin segments ----------------
// record: [fyq_b:19 @41][fxq_b:19 @22][yT:11 @11][xL:11 @0], q = round(-f*128)+2^18
__global__ __launch_bounds__(1024) void emit_k(const float* __restrict__ flow,
                                               int* __restrict__ cur,
                                               unsigned long long* __restrict__ recs) {
    __shared__ int hist[NW][NH];             // counts, then absolute per-wave cursors
    int bl = blockIdx.x / (Hn / RG);
    int g  = blockIdx.x % (Hn / RG);
    int y0 = g * RG;
    int wv = threadIdx.x >> 6;
    for (int i = threadIdx.x; i < NW * NH; i += 1024) ((int*)hist)[i] = 0;
    __syncthreads();

    const float* f = flow + (size_t)bl * 2 * HW;
    float cfx[10], cfy[10];
    #pragma unroll
    for (int k = 0; k < 10; ++k) {
        int i  = threadIdx.x + k * 1024;
        int ry = i / Wn;
        int x  = i - ry * Wn;
        int y  = y0 + ry;
        int p  = y * Wn + x;
        float fx = f[p];
        float fy = f[p + HW];
        cfx[k] = fx;
        cfy[k] = fy;
        float x2 = (float)x + fx;
        float y2 = (float)y + fy;
        if (!(x2 >= 0.f && y2 >= 0.f && x2 <= (float)(Wn - 1) && y2 <= (float)(Hn - 1)))
            continue;
        int yT  = (int)floorf(y2);
        int rel = yT - y0 + HALO;
        if (rel >= 0 && rel < NH) atomicAdd(&hist[wv][rel], 1);
    }
    __syncthreads();
    for (int i = threadIdx.x; i < NH; i += 1024) {
        int tot = 0;
        for (int w = 0; w < NW; ++w) tot += hist[w][i];
        int row = y0 - HALO + i;
        int run = 0;
        if (tot > 0 && row >= 0 && row < Hn)
            run = atomicAdd(&cur[bl * Hn + row], tot);
        for (int w = 0; w < NW; ++w) {
            int c = hist[w][i];
            hist[w][i] = run;
            run += c;
        }
    }
    __syncthreads();
    #pragma unroll
    for (int k = 0; k < 10; ++k) {
        int i  = threadIdx.x + k * 1024;
        int ry = i / Wn;
        int x  = i - ry * Wn;
        int y  = y0 + ry;
        float fx = cfx[k];
        float fy = cfy[k];
        float x2 = (float)x + fx;
        float y2 = (float)y + fy;
        if (!(x2 >= 0.f && y2 >= 0.f && x2 <= (float)(Wn - 1) && y2 <= (float)(Hn - 1)))
            continue;
        int xL = (int)floorf(x2); xL = max(0, min(xL, Wn - 1));
        int yT = (int)floorf(y2);
        int fxq = __float2int_rn(-fx * 128.f) + (1 << 18);   // in (0, 2^19)
        int fyq = __float2int_rn(-fy * 128.f) + (1 << 18);
        unsigned long long rec = (unsigned long long)(unsigned)xL
                               | ((unsigned long long)(unsigned)yT  << 11)
                               | ((unsigned long long)(unsigned)fxq << 22)
                               | ((unsigned long long)(unsigned)fyq << 41);
        int rel = yT - y0 + HALO;
        int slot;
        if (rel >= 0 && rel < NH) slot = atomicAdd(&hist[wv][rel], 1);
        else                      slot = atomicAdd(&cur[bl * Hn + yT], 1);   // outlier
        recs[slot] = rec;
    }
}

// ---------------- Pass B: strip u64-packed LDS accumulation + fused normalize ----------------
__global__ __launch_bounds__(512, 8) void accum_k(const int* __restrict__ off,
                                                  const unsigned long long* __restrict__ recs,
                                                  float* __restrict__ out,
                                                  unsigned long long* __restrict__ mask) {
    __shared__ unsigned long long accQ[SW];  // 40 KB: [fy:27][fx:27][cnt:10] per cell
    int bl = blockIdx.x / (Hn / S);
    int st = blockIdx.x % (Hn / S);
    int r0 = st * S;

    for (int i = threadIdx.x; i < SW; i += 512) accQ[i] = 0ull;
    __syncthreads();

    int rlo = max(r0 - 1, 0);
    int rhi = r0 + S - 1;
    int lo  = off[bl * Hn + rlo];
    int hi  = off[bl * Hn + rhi + 1];

    for (int j = lo + threadIdx.x; j < hi; j += 512) {
        unsigned long long rec = recs[j];
        int xL = (int)(rec & 0x7FFu);
        int yT = (int)((rec >> 11) & 0x7FFu);
        unsigned long long t = (((rec >> 41) & 0x7FFFFull) << 37)
                             | (((rec >> 22) & 0x7FFFFull) << 10) | 1ull;
        int xR = min(xL + 1, Wn - 1);
        int yB = min(yT + 1, Hn - 1);
        #pragma unroll
        for (int rr = 0; rr < 2; ++rr) {
            int row = rr ? yB : yT;          // yT==yB at bottom edge -> double add (matches ref)
            if (row >= r0 && row < r0 + S) {
                int rb = (row - r0) * Wn;
                atomicAdd(&accQ[rb + xL], t);
                atomicAdd(&accQ[rb + xR], t);   // xL==xR at right edge -> double add
            }
        }
    }
    __syncthreads();

    float* ox = out + (size_t)bl * 2 * HW;
    size_t pixbase = (size_t)bl * HW + (size_t)r0 * Wn;  // multiple of 64
    for (int i = threadIdx.x; i < SW; i += 512) {        // 10 iters, all lanes active
        int rw  = i / Wn;
        int col = i - rw * Wn;
        int p   = (r0 + rw) * Wn + col;
        unsigned long long v = accQ[i];
        unsigned c = (unsigned)(v & 1023ull);
        float vx = 0.f, vy = 0.f;
        if (c) {
            int sfx = (int)((v >> 10) & 0x7FFFFFFull) - (int)(c << 18);
            int sfy = (int)((v >> 37) & 0x7FFFFFFull) - (int)(c << 18);
            float inv = 1.f / (128.f * (float)c);
            vx = (float)sfx * inv;
            vy = (float)sfy * inv;
        }
        ox[p]      = vx;
        ox[p + HW] = vy;
        unsigned long long m = __ballot(c != 0);
        if ((threadIdx.x & 63) == 0) mask[(pixbase + (size_t)i) >> 6] = m;
    }
}

// ---------------- bit-transpose row mask -> column mask ----------------
// colmask[(b*Wn + x)*CW + w] bit j = mask bit for (b, row w*64+j, col x).
// In-register 64x64 bit transpose per wave (Hacker's Delight butterfly).
__global__ __launch_bounds__(256) void transpose_k(const unsigned long long* __restrict__ mask,
                                                   unsigned long long* __restrict__ colmask) {
    int tile = blockIdx.x * 4 + (threadIdx.x >> 6);   // (b, tY, xw)
    int lane = threadIdx.x & 63;
    int xw = tile % WPR;
    int tY = (tile / WPR) % CW;
    int b  = tile / (WPR * CW);
    int y  = tY * 64 + lane;

    unsigned long long x = 0ull;
    if (y < Hn) x = mask[(size_t)b * (HW / 64) + (size_t)y * WPR + xw];
    x = __builtin_bitreverse64(x);           // MSB-first convention for HD transpose

    unsigned long long m = 0x00000000FFFFFFFFull;
    #pragma unroll
    for (int j = 32; j != 0; j >>= 1, m ^= (m << j)) {
        unsigned long long p = __shfl_xor(x, j);
        bool hi = (lane & j) != 0;
        unsigned long long lo_w = hi ? p : x;
        unsigned long long hi_w = hi ? x : p;
        unsigned long long t = (lo_w ^ (hi_w >> j)) & m;
        x ^= hi ? (t << j) : t;
    }
    x = __builtin_bitreverse64(x);           // back to LSB = smallest row

    int col = xw * 64 + lane;
    colmask[((size_t)b * Wn + col) * CW + tY] = x;
}

// ---------------- compact holes into a dense list ----------------
// One thread per mask word; wave-prefix + ONE atomic per wave (3600 total).
__global__ __launch_bounds__(256) void compact_k(const unsigned long long* __restrict__ mask,
                                                 unsigned* __restrict__ holes,
                                                 unsigned* __restrict__ hole_cnt) {
    int w = blockIdx.x * 256 + threadIdx.x;          // grid sized exactly NWORDS
    int lane = threadIdx.x & 63;
    unsigned long long hb = ~mask[w];
    int cnt = __popcll(hb);
    int incl = cnt;
    #pragma unroll
    for (int d = 1; d < 64; d <<= 1) {
        int v = __shfl_up(incl, d);
        if (lane >= d) incl += v;
    }
    int total = __shfl(incl, 63);
    unsigned base = 0;
    if (total > 0) {
        if (lane == 63) base = atomicAdd(hole_cnt, (unsigned)total);
        base = (unsigned)__shfl((int)base, 63);
    }
    unsigned slot = base + (unsigned)(incl - cnt);
    unsigned gpb = (unsigned)w << 6;
    while (hb) {
        int b = __ffsll((long long)hb) - 1;
        holes[slot++] = gpb + (unsigned)b;
        hb &= hb - 1;
    }
}

// ---------------- hole fill: 4 lanes per hole (lane = direction) ----------------
__global__ __launch_bounds__(256) void fillc_k(float* __restrict__ out,
                                               const unsigned long long* __restrict__ mask,
                                               const unsigned long long* __restrict__ colmask,
                                               const unsigned* __restrict__ holes,
                                               const unsigned* __restrict__ hole_cnt) {
    int n = (int)*hole_cnt;
    long long tot = (long long)n << 2;
    for (long long i = (long long)blockIdx.x * 256 + threadIdx.x; i < tot;
         i += (long long)gridDim.x * 256) {
        int idx = (int)(i >> 2);
        int dir = (int)(i & 3);
        unsigned gp = holes[idx];
        int b = (int)(gp / (unsigned)HW);
        int p = (int)(gp - (unsigned)b * (unsigned)HW);
        int y = p / Wn;
        int x = p - y * Wn;
        float* ox = out + (size_t)b * 2 * HW;

        int q = -1;
        if (dir < 2) {
            const unsigned long long* rowmask = mask + (((size_t)b * HW + (size_t)y * Wn) >> 6);
            int bit = x & 63;
            if (dir == 0) {                  // nearest valid LEFT
                int w = x >> 6;
                unsigned long long m = bit ? (rowmask[w] & ((1ull << bit) - 1)) : 0ull;
                while (true) {
                    if (m) { q = y * Wn + ((w << 6) + 63 - __clzll(m)); break; }
                    if (--w < 0) break;
                    m = rowmask[w];
                }
            } else {                         // nearest valid RIGHT
                int w = x >> 6;
                unsigned long long m = rowmask[w] & ~((2ull << bit) - 1);   // bits > bit
                while (true) {
                    if (m) { q = y * Wn + ((w << 6) + __ffsll((long long)m) - 1); break; }
                    if (++w >= WPR) break;
                    m = rowmask[w];
                }
            }
        } else {
            const unsigned long long* cm = colmask + ((size_t)b * Wn + x) * CW;
            int rb = y & 63;
            if (dir == 2) {                  // nearest valid UP
                int w = y >> 6;
                unsigned long long m = rb ? (cm[w] & ((1ull << rb) - 1)) : 0ull;
                while (true) {
                    if (m) { q = ((w << 6) + 63 - __clzll(m)) * Wn + x; break; }
                    if (--w < 0) break;
                    m = cm[w];
                }
            } else {                         // nearest valid DOWN (bits >= Hn are 0)
                int w = y >> 6;
                unsigned long long m = cm[w] & ~((2ull << rb) - 1);
                while (true) {
                    if (m) { q = ((w << 6) + __ffsll((long long)m) - 1) * Wn + x; break; }
                    if (++w >= CW) break;
                    m = cm[w];
                }
            }
        }

        float vx = 0.f, vy = 0.f, fnd = 0.f;
        if (q >= 0) { vx = ox[q]; vy = ox[q + HW]; fnd = 1.f; }
        vx += __shfl_xor(vx, 1); vy += __shfl_xor(vy, 1); fnd += __shfl_xor(fnd, 1);
        vx += __shfl_xor(vx, 2); vy += __shfl_xor(vy, 2); fnd += __shfl_xor(fnd, 2);
        if (dir == 0 && fnd > 0.f) {
            ox[p]      = vx / fnd;
            ox[p + HW] = vy / fnd;
        }
    }
}

extern "C" void kernel_launch(void* const* d_in, const int* in_sizes, int n_in,
                              void* d_out, int out_size, void* d_ws, size_t ws_size,
                              hipStream_t stream) {
    const float* flow = (const float*)d_in[0];
    float* out = (float*)d_out;
    char* ws = (char*)d_ws;

    // ---- big layout (single chunk, 16 images): ~122 MB ----
    size_t recs16_b = (size_t)Bn * HW * 8;                 // 118.0 MB
    size_t mask_b   = (size_t)(TOT / 64) * 8;              // 1.84 MB
    size_t col_b    = (size_t)Bn * Wn * CW * 8;            // 1.97 MB
    size_t bins_b   = 4 * ((size_t)NBMAX * 4 + 256) + ((size_t)(NBMAX + 1) * 4) + 512;
    size_t need_big = recs16_b + mask_b + col_b + bins_b + 4096;
    bool big = ws_size >= need_big;

    int hbImgs = big ? 16 : 8;               // images per chunk
    int chunks = big ? 1 : 2;
    int nb = hbImgs * Hn;                    // bins per chunk
    size_t recs_b = (size_t)hbImgs * HW * 8;

    size_t o = 0;
    unsigned long long* recs = (unsigned long long*)(ws + o); o += recs_b;
    unsigned long long* mask = (unsigned long long*)(ws + o); o += mask_b;
    unsigned long long* colmask = (unsigned long long*)(ws + o); o += col_b;
    o = (o + 255) & ~(size_t)255;
    int* bin_count = (int*)(ws + o); o += (size_t)NBMAX * 4;
    o = (o + 255) & ~(size_t)255;
    int* off = (int*)(ws + o);       o += (size_t)(NBMAX + 1) * 4;
    o = (o + 255) & ~(size_t)255;
    int* cur = (int*)(ws + o);       o += (size_t)NBMAX * 4;
    o = (o + 255) & ~(size_t)255;
    unsigned* hole_cnt = (unsigned*)(ws + o); o += 4;

    // hole list reuses recs (dead after last accum_k): capacity TOT u32 fits easily
    unsigned* holes = (unsigned*)recs;

    const int bin_blocks   = hbImgs * (Hn / RG);   // 1440 (big) / 720
    const int strip_blocks = hbImgs * (Hn / S);    // 2880 (big) / 1440

    for (int chunk = 0; chunk < chunks; ++chunk) {
        const float* fchunk = flow + (size_t)chunk * hbImgs * 2 * HW;
        float* ochunk = out + (size_t)chunk * hbImgs * 2 * HW;
        unsigned long long* mchunk = mask + (size_t)chunk * ((size_t)hbImgs * HW / 64);

        hipMemsetAsync(bin_count, 0, (size_t)nb * 4, stream);
        count_k<<<bin_blocks, 1024, 0, stream>>>(fchunk, bin_count);
        scan_k<<<1, 1024, 0, stream>>>(bin_count, off, cur, nb);
        emit_k<<<bin_blocks, 1024, 0, stream>>>(fchunk, cur, recs);
        accum_k<<<strip_blocks, 512, 0, stream>>>(off, recs, ochunk, mchunk);
    }

    hipMemsetAsync(hole_cnt, 0, 4, stream);

    const int tr_tiles = Bn * CW * WPR;                 // 3840 tiles
    transpose_k<<<tr_tiles / 4, 256, 0, stream>>>(mask, colmask);
    compact_k<<<NWORDS / 256, 256, 0, stream>>>(mask, holes, hole_cnt);
    fillc_k<<<2048, 256, 0, stream>>>(out, mask, colmask, holes, hole_cnt);
}